// Round 1
// baseline (2187.886 us; speedup 1.0000x reference)
//
#include <hip/hip_runtime.h>
#include <hip/hip_bf16.h>
#include <math.h>

#define BB 8
#define CC 128
#define HH 128
#define WW 128
#define HWW (HH*WW)

// ---------------- Kernel 1: fused QK + V projection ----------------
// out: qk[p][256] (q cols 0..127, k cols 128..255), v[p][128]
__global__ __launch_bounds__(256) void k_proj(
    const float* __restrict__ x, const float* __restrict__ w_qk,
    const float* __restrict__ b_qk, const float* __restrict__ w_v,
    const float* __restrict__ b_v, float* __restrict__ qk, float* __restrict__ v)
{
    __shared__ float Xs[128 * 64];          // [c][px] tile, conflict-free reads
    const int tid = threadIdx.x;
    const int blk = blockIdx.x;
    const int b = blk >> 8, rem = blk & 255;
    const int i = rem >> 1, j0 = (rem & 1) << 6;   // 64 pixels along W
    const float* xb = x + (size_t)b * CC * HWW + i * WW + j0;
    #pragma unroll
    for (int it = 0; it < 32; ++it) {
        int idx = tid + it * 256;
        int c = idx >> 6, jj = idx & 63;
        Xs[idx] = xb[(size_t)c * HWW + jj];  // coalesced along jj
    }
    __syncthreads();
    const int px = tid & 63, g = tid >> 6;   // 4 column-groups of 96
    const size_t p = (size_t)b * HWW + i * WW + j0 + px;
    for (int ch = 0; ch < 6; ++ch) {
        const int n0 = g * 96 + ch * 16;     // 16-wide n chunk, never straddles 256
        const float* wp; const float* bp; float* op; int stride;
        if (n0 < 256) { wp = w_qk + n0; bp = b_qk + n0; op = qk + p * 256 + n0; stride = 256; }
        else { int nv = n0 - 256; wp = w_v + nv; bp = b_v + nv; op = v + p * 128 + nv; stride = 128; }
        float acc[16];
        #pragma unroll
        for (int e = 0; e < 16; ++e) acc[e] = bp[e];
        #pragma unroll 4
        for (int k = 0; k < 128; ++k) {
            float xv = Xs[k * 64 + px];
            const float4* wr = (const float4*)(wp + (size_t)k * stride);
            #pragma unroll
            for (int q4 = 0; q4 < 4; ++q4) {
                float4 wv = wr[q4];
                acc[q4*4+0] = fmaf(xv, wv.x, acc[q4*4+0]);
                acc[q4*4+1] = fmaf(xv, wv.y, acc[q4*4+1]);
                acc[q4*4+2] = fmaf(xv, wv.z, acc[q4*4+2]);
                acc[q4*4+3] = fmaf(xv, wv.w, acc[q4*4+3]);
            }
        }
        float4* o4 = (float4*)op;
        #pragma unroll
        for (int q4 = 0; q4 < 4; ++q4)
            o4[q4] = make_float4(acc[q4*4+0], acc[q4*4+1], acc[q4*4+2], acc[q4*4+3]);
    }
}

// ---------------- Kernel 2: superpixel-similarity dots (pwd) ----------------
#define SSTR 260   // 256 + pad: keeps float4 alignment, spreads banks
__global__ __launch_bounds__(256) void k_pwd(
    const float* __restrict__ sims, float* __restrict__ pwd)
{
    extern __shared__ float Ss[];            // [144][SSTR]  (12x12 halo of 256-f vectors)
    const int tid = threadIdx.x;
    const int blk = blockIdx.x;
    const int b = blk >> 8, tile = blk & 255;
    const int i0 = (tile >> 4) << 3, j0 = (tile & 15) << 3;   // 8x8 pixel tile
    #pragma unroll
    for (int it = 0; it < 36; ++it) {
        int idx = tid + it * 256;            // 144 vecs * 64 float4
        int vec = idx >> 6, s4 = (idx & 63) << 2;
        int hi = vec / 12, wj = vec - hi * 12;
        int ii = i0 - 2 + hi, jj = j0 - 2 + wj;
        float4 val = make_float4(0.f, 0.f, 0.f, 0.f);
        if ((unsigned)ii < 128u && (unsigned)jj < 128u)
            val = *(const float4*)(sims + ((((size_t)b * HH + ii) * WW + jj) << 8) + s4);
        float* d = Ss + vec * SSTR + s4;
        d[0] = val.x; d[1] = val.y; d[2] = val.z; d[3] = val.w;
    }
    __syncthreads();
    const int px = tid & 63, og = tid >> 6;  // 4 offset-groups (wave-uniform)
    const int pi = px >> 3, pj = px & 7;
    const float* selfp = Ss + ((pi + 2) * 12 + (pj + 2)) * SSTR;
    const int noffs = (og == 0) ? 7 : 6;     // og covers offsets og, og+4, ...
    const float* nb[7];
    int offl[7];
    #pragma unroll
    for (int m = 0; m < 7; ++m) {
        int off = og + (m << 2);
        if (off > 24) off = 24;              // dummy (unused when m>=noffs)
        offl[m] = off;
        int di = off / 5, dj = off - 5 * di;
        nb[m] = Ss + ((pi + di) * 12 + (pj + dj)) * SSTR;
    }
    float acc[7] = {0.f,0.f,0.f,0.f,0.f,0.f,0.f};
    for (int s0 = 0; s0 < 256; s0 += 16) {
        float4 a0 = *(const float4*)(selfp + s0);
        float4 a1 = *(const float4*)(selfp + s0 + 4);
        float4 a2 = *(const float4*)(selfp + s0 + 8);
        float4 a3 = *(const float4*)(selfp + s0 + 12);
        #pragma unroll
        for (int m = 0; m < 7; ++m) {
            if (m < noffs) {
                const float4* q = (const float4*)(nb[m] + s0);
                float4 b0 = q[0], b1 = q[1], b2 = q[2], b3 = q[3];
                float s = acc[m];
                s = fmaf(a0.x, b0.x, s); s = fmaf(a0.y, b0.y, s);
                s = fmaf(a0.z, b0.z, s); s = fmaf(a0.w, b0.w, s);
                s = fmaf(a1.x, b1.x, s); s = fmaf(a1.y, b1.y, s);
                s = fmaf(a1.z, b1.z, s); s = fmaf(a1.w, b1.w, s);
                s = fmaf(a2.x, b2.x, s); s = fmaf(a2.y, b2.y, s);
                s = fmaf(a2.z, b2.z, s); s = fmaf(a2.w, b2.w, s);
                s = fmaf(a3.x, b3.x, s); s = fmaf(a3.y, b3.y, s);
                s = fmaf(a3.z, b3.z, s); s = fmaf(a3.w, b3.w, s);
                acc[m] = s;
            }
        }
    }
    const size_t p = (size_t)b * HWW + (i0 + pi) * WW + (j0 + pj);
    #pragma unroll
    for (int m = 0; m < 7; ++m)
        if (m < noffs) pwd[p * 25 + offl[m]] = acc[m];
}

// ---------------- Kernel 3: scores + softmax + pwd reweight + V aggregation ----------------
#define KSTR 132
__global__ __launch_bounds__(256) void k_attn(
    const float* __restrict__ qk, const float* __restrict__ vbuf,
    const float* __restrict__ pwd, float* __restrict__ y)
{
    extern __shared__ float Hs[];            // [144][KSTR], K halo then V halo
    const int tid = threadIdx.x, blk = blockIdx.x;
    const int b = blk >> 8, tile = blk & 255;
    const int i0 = (tile >> 4) << 3, j0 = (tile & 15) << 3;
    // stage K halo
    #pragma unroll
    for (int it = 0; it < 18; ++it) {
        int idx = tid + it * 256;            // 144 vecs * 32 float4
        int vec = idx >> 5, c4 = (idx & 31) << 2;
        int hi = vec / 12, wj = vec - hi * 12;
        int ii = i0 - 2 + hi, jj = j0 - 2 + wj;
        float4 val = make_float4(0.f, 0.f, 0.f, 0.f);
        if ((unsigned)ii < 128u && (unsigned)jj < 128u)
            val = *(const float4*)(qk + ((((size_t)b * HH + ii) * WW + jj) << 8) + 128 + c4);
        float* d = Hs + vec * KSTR + c4;
        d[0] = val.x; d[1] = val.y; d[2] = val.z; d[3] = val.w;
    }
    __syncthreads();
    const int px = tid & 63, h = tid >> 6;   // wave == head
    const int pi = px >> 3, pj = px & 7;
    const size_t p = (size_t)b * HWW + (size_t)(i0 + pi) * WW + (j0 + pj);
    float qreg[32];
    {
        const float4* qp = (const float4*)(qk + p * 256 + h * 32);
        #pragma unroll
        for (int e = 0; e < 8; ++e) {
            float4 t = qp[e];
            qreg[e*4+0] = t.x; qreg[e*4+1] = t.y; qreg[e*4+2] = t.z; qreg[e*4+3] = t.w;
        }
    }
    float sc[25];
    #pragma unroll
    for (int off = 0; off < 25; ++off) {
        int di = off / 5, dj = off - 5 * di;
        const float4* kp = (const float4*)(Hs + ((pi + di) * 12 + (pj + dj)) * KSTR + h * 32);
        float s = 0.f;
        #pragma unroll
        for (int e = 0; e < 8; ++e) {
            float4 kv = kp[e];
            s = fmaf(qreg[e*4+0], kv.x, s); s = fmaf(qreg[e*4+1], kv.y, s);
            s = fmaf(qreg[e*4+2], kv.z, s); s = fmaf(qreg[e*4+3], kv.w, s);
        }
        sc[off] = s * 0.17677669529663687f;   // HD^-0.5
    }
    float mx = sc[0];
    #pragma unroll
    for (int off = 1; off < 25; ++off) mx = fmaxf(mx, sc[off]);
    float den = 0.f;
    #pragma unroll
    for (int off = 0; off < 25; ++off) { sc[off] = __expf(sc[off] - mx); den += sc[off]; }
    const float inv = 1.f / den;
    float den2 = 0.f;
    #pragma unroll
    for (int off = 0; off < 25; ++off) {
        float t = sc[off] * inv * pwd[p * 25 + off];
        sc[off] = t; den2 += t;
    }
    const float wnorm = 1.f / fmaxf(den2, 1e-8f);
    __syncthreads();                          // done reading K halo
    // stage V halo (overwrite)
    #pragma unroll
    for (int it = 0; it < 18; ++it) {
        int idx = tid + it * 256;
        int vec = idx >> 5, c4 = (idx & 31) << 2;
        int hi = vec / 12, wj = vec - hi * 12;
        int ii = i0 - 2 + hi, jj = j0 - 2 + wj;
        float4 val = make_float4(0.f, 0.f, 0.f, 0.f);
        if ((unsigned)ii < 128u && (unsigned)jj < 128u)
            val = *(const float4*)(vbuf + ((((size_t)b * HH + ii) * WW + jj) << 7) + c4);
        float* d = Hs + vec * KSTR + c4;
        d[0] = val.x; d[1] = val.y; d[2] = val.z; d[3] = val.w;
    }
    __syncthreads();
    float acc[32];
    #pragma unroll
    for (int e = 0; e < 32; ++e) acc[e] = 0.f;
    #pragma unroll
    for (int off = 0; off < 25; ++off) {
        int di = off / 5, dj = off - 5 * di;
        const float4* vp = (const float4*)(Hs + ((pi + di) * 12 + (pj + dj)) * KSTR + h * 32);
        float w = sc[off] * wnorm;
        #pragma unroll
        for (int e = 0; e < 8; ++e) {
            float4 vv = vp[e];
            acc[e*4+0] = fmaf(w, vv.x, acc[e*4+0]); acc[e*4+1] = fmaf(w, vv.y, acc[e*4+1]);
            acc[e*4+2] = fmaf(w, vv.z, acc[e*4+2]); acc[e*4+3] = fmaf(w, vv.w, acc[e*4+3]);
        }
    }
    float4* yo = (float4*)(y + p * 128 + h * 32);
    #pragma unroll
    for (int e = 0; e < 8; ++e)
        yo[e] = make_float4(acc[e*4+0], acc[e*4+1], acc[e*4+2], acc[e*4+3]);
}

// ---------------- Kernel 4: output projection + NCHW transpose ----------------
__global__ __launch_bounds__(256) void k_out(
    const float* __restrict__ y, const float* __restrict__ w_proj,
    const float* __restrict__ b_proj, float* __restrict__ out)
{
    __shared__ float Ys[128 * 65];           // [c][px], pad 65
    const int tid = threadIdx.x, blk = blockIdx.x;
    const int b = blk >> 8, rem = blk & 255;
    const int i = rem >> 1, j0 = (rem & 1) << 6;
    const size_t p0 = (size_t)b * HWW + i * WW + j0;
    #pragma unroll
    for (int it = 0; it < 8; ++it) {
        int f4 = tid + it * 256;             // 64 px * 32 float4
        int pl = f4 >> 5, c4 = (f4 & 31) << 2;
        float4 val = *(const float4*)(y + (p0 + pl) * 128 + c4);
        Ys[(c4 + 0) * 65 + pl] = val.x; Ys[(c4 + 1) * 65 + pl] = val.y;
        Ys[(c4 + 2) * 65 + pl] = val.z; Ys[(c4 + 3) * 65 + pl] = val.w;
    }
    __syncthreads();
    const int px = tid & 63, g = tid >> 6;
    for (int ch = 0; ch < 2; ++ch) {
        const int n0 = g * 32 + ch * 16;
        float acc[16];
        #pragma unroll
        for (int e = 0; e < 16; ++e) acc[e] = b_proj[n0 + e];
        #pragma unroll 4
        for (int k = 0; k < 128; ++k) {
            float yv = Ys[k * 65 + px];
            const float4* wr = (const float4*)(w_proj + (size_t)k * 128 + n0);
            #pragma unroll
            for (int q4 = 0; q4 < 4; ++q4) {
                float4 wv = wr[q4];
                acc[q4*4+0] = fmaf(yv, wv.x, acc[q4*4+0]);
                acc[q4*4+1] = fmaf(yv, wv.y, acc[q4*4+1]);
                acc[q4*4+2] = fmaf(yv, wv.z, acc[q4*4+2]);
                acc[q4*4+3] = fmaf(yv, wv.w, acc[q4*4+3]);
            }
        }
        float* ob = out + ((size_t)b * CC + n0) * HWW + (size_t)i * WW + j0 + px;
        #pragma unroll
        for (int e = 0; e < 16; ++e) ob[(size_t)e * HWW] = acc[e];   // coalesced per e
    }
}

extern "C" void kernel_launch(void* const* d_in, const int* in_sizes, int n_in,
                              void* d_out, int out_size, void* d_ws, size_t ws_size,
                              hipStream_t stream) {
    (void)in_sizes; (void)n_in; (void)out_size; (void)ws_size;
    const float* x      = (const float*)d_in[0];
    const float* sims   = (const float*)d_in[1];
    const float* w_qk   = (const float*)d_in[2];
    const float* b_qk   = (const float*)d_in[3];
    const float* w_v    = (const float*)d_in[4];
    const float* b_v    = (const float*)d_in[5];
    const float* w_proj = (const float*)d_in[6];
    const float* b_proj = (const float*)d_in[7];
    float* out = (float*)d_out;
    float* ws  = (float*)d_ws;
    float* qk  = ws;                       // 131072*256 = 33,554,432 f
    float* v   = ws + 33554432ull;         // 131072*128 = 16,777,216 f
    float* pwd = ws + 50331648ull;         // 131072*25  =  3,276,800 f
    float* y   = ws + 53608448ull;         // 131072*128 = 16,777,216 f
    dim3 blkd(256);
    hipLaunchKernelGGL(k_proj, dim3(2048), blkd, 0, stream, x, w_qk, b_qk, w_v, b_v, qk, v);
    hipLaunchKernelGGL(k_pwd,  dim3(2048), blkd, 144 * SSTR * 4, stream, sims, pwd);
    hipLaunchKernelGGL(k_attn, dim3(2048), blkd, 144 * KSTR * 4, stream, qk, v, pwd, y);
    hipLaunchKernelGGL(k_out,  dim3(2048), blkd, 0, stream, y, w_proj, b_proj, out);
}

// Round 2
// 2047.687 us; speedup vs baseline: 1.0685x; 1.0685x over previous
//
#include <hip/hip_runtime.h>
#include <hip/hip_bf16.h>
#include <math.h>

#define BB 8
#define CC 128
#define HH 128
#define WW 128
#define HWW (HH*WW)
#define PTOT (BB*HWW)     // 131072 pixels

// ---------------- Kernel 1: fused QK + V projection ----------------
// out: qk[p][256] (q cols 0..127, k cols 128..255), v[p][128]
__global__ __launch_bounds__(256) void k_proj(
    const float* __restrict__ x, const float* __restrict__ w_qk,
    const float* __restrict__ b_qk, const float* __restrict__ w_v,
    const float* __restrict__ b_v, float* __restrict__ qk, float* __restrict__ v)
{
    __shared__ float Xs[128 * 64];          // [c][px] tile, conflict-free reads
    const int tid = threadIdx.x;
    const int blk = blockIdx.x;
    const int b = blk >> 8, rem = blk & 255;
    const int i = rem >> 1, j0 = (rem & 1) << 6;   // 64 pixels along W
    const float* xb = x + (size_t)b * CC * HWW + i * WW + j0;
    #pragma unroll
    for (int it = 0; it < 32; ++it) {
        int idx = tid + it * 256;
        int c = idx >> 6, jj = idx & 63;
        Xs[idx] = xb[(size_t)c * HWW + jj];  // coalesced along jj
    }
    __syncthreads();
    const int px = tid & 63, g = tid >> 6;   // 4 column-groups of 96
    const size_t p = (size_t)b * HWW + i * WW + j0 + px;
    for (int ch = 0; ch < 6; ++ch) {
        const int n0 = g * 96 + ch * 16;     // 16-wide n chunk, never straddles 256
        const float* wp; const float* bp; float* op; int stride;
        if (n0 < 256) { wp = w_qk + n0; bp = b_qk + n0; op = qk + p * 256 + n0; stride = 256; }
        else { int nv = n0 - 256; wp = w_v + nv; bp = b_v + nv; op = v + p * 128 + nv; stride = 128; }
        float acc[16];
        #pragma unroll
        for (int e = 0; e < 16; ++e) acc[e] = bp[e];
        #pragma unroll 4
        for (int k = 0; k < 128; ++k) {
            float xv = Xs[k * 64 + px];
            const float4* wr = (const float4*)(wp + (size_t)k * stride);
            #pragma unroll
            for (int q4 = 0; q4 < 4; ++q4) {
                float4 wv = wr[q4];
                acc[q4*4+0] = fmaf(xv, wv.x, acc[q4*4+0]);
                acc[q4*4+1] = fmaf(xv, wv.y, acc[q4*4+1]);
                acc[q4*4+2] = fmaf(xv, wv.z, acc[q4*4+2]);
                acc[q4*4+3] = fmaf(xv, wv.w, acc[q4*4+3]);
            }
        }
        float4* o4 = (float4*)op;
        #pragma unroll
        for (int q4 = 0; q4 < 4; ++q4)
            o4[q4] = make_float4(acc[q4*4+0], acc[q4*4+1], acc[q4*4+2], acc[q4*4+3]);
    }
}

// ---------------- Kernel 2: superpixel-similarity dots (pwd) ----------------
// pwd layout: [off][p]  (transposed -> coalesced writes here, coalesced reads in k_attn)
#define SSTR 260
__global__ __launch_bounds__(256) void k_pwd(
    const float* __restrict__ sims, float* __restrict__ pwd)
{
    extern __shared__ float Ss[];            // [144][SSTR]  (12x12 halo of 256-f vectors)
    const int tid = threadIdx.x;
    const int blk = blockIdx.x;
    const int b = blk >> 8, tile = blk & 255;
    const int i0 = (tile >> 4) << 3, j0 = (tile & 15) << 3;   // 8x8 pixel tile
    #pragma unroll 6
    for (int it = 0; it < 36; ++it) {
        int idx = tid + it * 256;            // 144 vecs * 64 float4
        int vec = idx >> 6, s4 = (idx & 63) << 2;
        int hi = vec / 12, wj = vec - hi * 12;
        int ii = i0 - 2 + hi, jj = j0 - 2 + wj;
        float4 val = make_float4(0.f, 0.f, 0.f, 0.f);
        if ((unsigned)ii < 128u && (unsigned)jj < 128u)
            val = *(const float4*)(sims + ((((size_t)b * HH + ii) * WW + jj) << 8) + s4);
        *(float4*)(Ss + vec * SSTR + s4) = val;
    }
    __syncthreads();
    const int px = tid & 63, og = tid >> 6;  // 4 offset-groups (wave-uniform)
    const int pi = px >> 3, pj = px & 7;
    const float* selfp = Ss + ((pi + 2) * 12 + (pj + 2)) * SSTR;
    const int noffs = (og == 0) ? 7 : 6;     // og covers offsets og, og+4, ...
    const float* nb[7];
    int offl[7];
    #pragma unroll
    for (int m = 0; m < 7; ++m) {
        int off = og + (m << 2);
        if (off > 24) off = 24;              // dummy (unused when m>=noffs)
        offl[m] = off;
        int di = off / 5, dj = off - 5 * di;
        nb[m] = Ss + ((pi + di) * 12 + (pj + dj)) * SSTR;
    }
    float acc[7] = {0.f,0.f,0.f,0.f,0.f,0.f,0.f};
    for (int s0 = 0; s0 < 256; s0 += 16) {
        float4 a0 = *(const float4*)(selfp + s0);
        float4 a1 = *(const float4*)(selfp + s0 + 4);
        float4 a2 = *(const float4*)(selfp + s0 + 8);
        float4 a3 = *(const float4*)(selfp + s0 + 12);
        #pragma unroll
        for (int m = 0; m < 7; ++m) {
            if (m < noffs) {
                const float4* q = (const float4*)(nb[m] + s0);
                float4 b0 = q[0], b1 = q[1], b2 = q[2], b3 = q[3];
                float s = acc[m];
                s = fmaf(a0.x, b0.x, s); s = fmaf(a0.y, b0.y, s);
                s = fmaf(a0.z, b0.z, s); s = fmaf(a0.w, b0.w, s);
                s = fmaf(a1.x, b1.x, s); s = fmaf(a1.y, b1.y, s);
                s = fmaf(a1.z, b1.z, s); s = fmaf(a1.w, b1.w, s);
                s = fmaf(a2.x, b2.x, s); s = fmaf(a2.y, b2.y, s);
                s = fmaf(a2.z, b2.z, s); s = fmaf(a2.w, b2.w, s);
                s = fmaf(a3.x, b3.x, s); s = fmaf(a3.y, b3.y, s);
                s = fmaf(a3.z, b3.z, s); s = fmaf(a3.w, b3.w, s);
                acc[m] = s;
            }
        }
    }
    const int p = b * HWW + (i0 + pi) * WW + (j0 + pj);
    #pragma unroll
    for (int m = 0; m < 7; ++m)
        if (m < noffs) pwd[offl[m] * PTOT + p] = acc[m];   // coalesced per off
}

// ---------------- Kernel 3: scores + softmax + pwd reweight + V aggregation ----------------
// Channel-chunked (8 at a time) to keep VGPR < 128 -> no spills (R1: 256 VGPR + 1 GB scratch)
#define KSTR 132
__device__ __forceinline__ void stage_halo(
    float* Hs, const float* __restrict__ src, int pxstride, int b, int i0, int j0, int tid)
{
    #pragma unroll 6
    for (int it = 0; it < 18; ++it) {
        int idx = tid + it * 256;            // 144 vecs * 32 float4
        int vec = idx >> 5, c4 = (idx & 31) << 2;
        int hi = vec / 12, wj = vec - hi * 12;
        int ii = i0 - 2 + hi, jj = j0 - 2 + wj;
        float4 val = make_float4(0.f, 0.f, 0.f, 0.f);
        if ((unsigned)ii < 128u && (unsigned)jj < 128u)
            val = *(const float4*)(src + (((size_t)b * HH + ii) * WW + jj) * (size_t)pxstride + c4);
        *(float4*)(Hs + vec * KSTR + c4) = val;
    }
}

__global__ __launch_bounds__(256) void k_attn(
    const float* __restrict__ qk, const float* __restrict__ vbuf,
    const float* __restrict__ pwd, float* __restrict__ y)
{
    extern __shared__ float Hs[];            // [144][KSTR], K halo then V halo
    const int tid = threadIdx.x, blk = blockIdx.x;
    const int b = blk >> 8, tile = blk & 255;
    const int i0 = (tile >> 4) << 3, j0 = (tile & 15) << 3;
    stage_halo(Hs, qk + 128, 256, b, i0, j0, tid);      // K halo
    __syncthreads();
    const int px = tid & 63, h = tid >> 6;   // wave == head
    const int pi = px >> 3, pj = px & 7;
    const int p = b * HWW + (i0 + pi) * WW + (j0 + pj);
    const float* qb = qk + (size_t)p * 256 + h * 32;
    const float* hb = Hs + (pi * 12 + pj) * KSTR + h * 32;
    float sc[25];
    #pragma unroll
    for (int o = 0; o < 25; ++o) sc[o] = 0.f;
    #pragma unroll
    for (int ec = 0; ec < 4; ++ec) {         // 8 channels per chunk
        float4 q0 = *(const float4*)(qb + ec * 8);
        float4 q1 = *(const float4*)(qb + ec * 8 + 4);
        #pragma unroll
        for (int off = 0; off < 25; ++off) {
            const int voff = (off / 5) * 12 + (off % 5);
            const float* kp = hb + voff * KSTR + ec * 8;
            float4 k0 = *(const float4*)(kp);
            float4 k1 = *(const float4*)(kp + 4);
            float s = sc[off];
            s = fmaf(q0.x, k0.x, s); s = fmaf(q0.y, k0.y, s);
            s = fmaf(q0.z, k0.z, s); s = fmaf(q0.w, k0.w, s);
            s = fmaf(q1.x, k1.x, s); s = fmaf(q1.y, k1.y, s);
            s = fmaf(q1.z, k1.z, s); s = fmaf(q1.w, k1.w, s);
            sc[off] = s;
        }
    }
    float mx = sc[0] ;
    #pragma unroll
    for (int o = 1; o < 25; ++o) mx = fmaxf(mx, sc[o]);
    float den = 0.f;
    #pragma unroll
    for (int o = 0; o < 25; ++o) {
        sc[o] = __expf((sc[o] - mx) * 0.17677669529663687f);
        den += sc[o];
    }
    const float inv = 1.f / den;
    float den2 = 0.f;
    #pragma unroll
    for (int o = 0; o < 25; ++o) {
        float t = sc[o] * inv * pwd[o * PTOT + p];      // coalesced
        sc[o] = t; den2 += t;
    }
    const float wnorm = 1.f / fmaxf(den2, 1e-8f);
    #pragma unroll
    for (int o = 0; o < 25; ++o) sc[o] *= wnorm;
    __syncthreads();                          // done reading K halo
    stage_halo(Hs, vbuf, 128, b, i0, j0, tid);          // V halo (overwrite)
    __syncthreads();
    float4* yo = (float4*)(y + (size_t)p * 128 + h * 32);
    #pragma unroll
    for (int ec = 0; ec < 4; ++ec) {
        float4 a0 = make_float4(0.f, 0.f, 0.f, 0.f);
        float4 a1 = make_float4(0.f, 0.f, 0.f, 0.f);
        #pragma unroll
        for (int off = 0; off < 25; ++off) {
            const int voff = (off / 5) * 12 + (off % 5);
            const float* vp = hb + voff * KSTR + ec * 8;
            float4 v0 = *(const float4*)(vp);
            float4 v1 = *(const float4*)(vp + 4);
            float w = sc[off];
            a0.x = fmaf(w, v0.x, a0.x); a0.y = fmaf(w, v0.y, a0.y);
            a0.z = fmaf(w, v0.z, a0.z); a0.w = fmaf(w, v0.w, a0.w);
            a1.x = fmaf(w, v1.x, a1.x); a1.y = fmaf(w, v1.y, a1.y);
            a1.z = fmaf(w, v1.z, a1.z); a1.w = fmaf(w, v1.w, a1.w);
        }
        yo[ec * 2] = a0;
        yo[ec * 2 + 1] = a1;
    }
}

// ---------------- Kernel 4: output projection + NCHW transpose ----------------
__global__ __launch_bounds__(256) void k_out(
    const float* __restrict__ y, const float* __restrict__ w_proj,
    const float* __restrict__ b_proj, float* __restrict__ out)
{
    __shared__ float Ys[128 * 65];           // [c][px], pad 65
    const int tid = threadIdx.x, blk = blockIdx.x;
    const int b = blk >> 8, rem = blk & 255;
    const int i = rem >> 1, j0 = (rem & 1) << 6;
    const size_t p0 = (size_t)b * HWW + i * WW + j0;
    #pragma unroll
    for (int it = 0; it < 8; ++it) {
        int f4 = tid + it * 256;             // 64 px * 32 float4
        int pl = f4 >> 5, c4 = (f4 & 31) << 2;
        float4 val = *(const float4*)(y + (p0 + pl) * 128 + c4);
        Ys[(c4 + 0) * 65 + pl] = val.x; Ys[(c4 + 1) * 65 + pl] = val.y;
        Ys[(c4 + 2) * 65 + pl] = val.z; Ys[(c4 + 3) * 65 + pl] = val.w;
    }
    __syncthreads();
    const int px = tid & 63, g = tid >> 6;
    for (int ch = 0; ch < 2; ++ch) {
        const int n0 = g * 32 + ch * 16;
        float acc[16];
        #pragma unroll
        for (int e = 0; e < 16; ++e) acc[e] = b_proj[n0 + e];
        #pragma unroll 4
        for (int k = 0; k < 128; ++k) {
            float yv = Ys[k * 65 + px];
            const float4* wr = (const float4*)(w_proj + (size_t)k * 128 + n0);
            #pragma unroll
            for (int q4 = 0; q4 < 4; ++q4) {
                float4 wv = wr[q4];
                acc[q4*4+0] = fmaf(yv, wv.x, acc[q4*4+0]);
                acc[q4*4+1] = fmaf(yv, wv.y, acc[q4*4+1]);
                acc[q4*4+2] = fmaf(yv, wv.z, acc[q4*4+2]);
                acc[q4*4+3] = fmaf(yv, wv.w, acc[q4*4+3]);
            }
        }
        float* ob = out + ((size_t)b * CC + n0) * HWW + (size_t)i * WW + j0 + px;
        #pragma unroll
        for (int e = 0; e < 16; ++e) ob[(size_t)e * HWW] = acc[e];   // coalesced per e
    }
}

extern "C" void kernel_launch(void* const* d_in, const int* in_sizes, int n_in,
                              void* d_out, int out_size, void* d_ws, size_t ws_size,
                              hipStream_t stream) {
    (void)in_sizes; (void)n_in; (void)out_size; (void)ws_size;
    const float* x      = (const float*)d_in[0];
    const float* sims   = (const float*)d_in[1];
    const float* w_qk   = (const float*)d_in[2];
    const float* b_qk   = (const float*)d_in[3];
    const float* w_v    = (const float*)d_in[4];
    const float* b_v    = (const float*)d_in[5];
    const float* w_proj = (const float*)d_in[6];
    const float* b_proj = (const float*)d_in[7];
    float* out = (float*)d_out;
    float* ws  = (float*)d_ws;
    float* qk  = ws;                       // 131072*256 = 33,554,432 f
    float* v   = ws + 33554432ull;         // 131072*128 = 16,777,216 f
    float* pwd = ws + 50331648ull;         // 25*131072  =  3,276,800 f  [off][p]
    float* y   = ws + 53608448ull;         // 131072*128 = 16,777,216 f
    dim3 blkd(256);
    hipLaunchKernelGGL(k_proj, dim3(2048), blkd, 0, stream, x, w_qk, b_qk, w_v, b_v, qk, v);
    hipLaunchKernelGGL(k_pwd,  dim3(2048), blkd, 144 * SSTR * 4, stream, sims, pwd);
    hipLaunchKernelGGL(k_attn, dim3(2048), blkd, 144 * KSTR * 4, stream, qk, v, pwd, y);
    hipLaunchKernelGGL(k_out,  dim3(2048), blkd, 0, stream, y, w_proj, b_proj, out);
}

// Round 4
// 1226.087 us; speedup vs baseline: 1.7844x; 1.6701x over previous
//
#include <hip/hip_runtime.h>
#include <hip/hip_bf16.h>
#include <math.h>

#define BB 8
#define CC 128
#define HH 128
#define WW 128
#define HWW (HH*WW)
#define PTOT (BB*HWW)     // 131072 pixels

typedef __attribute__((ext_vector_type(8))) short bf16x8;
typedef __attribute__((ext_vector_type(4))) float f32x4;
typedef __attribute__((ext_vector_type(4))) unsigned short u16x4;
#define MFMA16(a,b,c) __builtin_amdgcn_mfma_f32_16x16x32_bf16(a,b,c,0,0,0)

__device__ __forceinline__ unsigned short f2bf(float f) {
    unsigned u = __builtin_bit_cast(unsigned, f);
    return (unsigned short)((u + 0x7fffu + ((u >> 16) & 1u)) >> 16);   // RNE
}
__device__ __forceinline__ float bf2f(unsigned short h) {
    unsigned u = ((unsigned)h) << 16;
    return __builtin_bit_cast(float, u);
}

// ---------------- Kernel 0: weight transpose + bf16 hi/lo split ----------------
// Wt[n=384][k=128]  (n<256 from w_qk, else w_v);  Wpt[n=128][k=128] from w_proj
__global__ __launch_bounds__(256) void k_prep(
    const float* __restrict__ wqk, const float* __restrict__ wv,
    const float* __restrict__ wp,
    unsigned short* __restrict__ Wt_hi, unsigned short* __restrict__ Wt_lo,
    unsigned short* __restrict__ Wpt_hi, unsigned short* __restrict__ Wpt_lo)
{
    int idx = blockIdx.x * 256 + threadIdx.x;
    if (idx < 384 * 128) {
        int n = idx >> 7, k = idx & 127;
        float w = (n < 256) ? wqk[k * 256 + n] : wv[k * 128 + (n - 256)];
        unsigned short h = f2bf(w);
        Wt_hi[idx] = h;
        Wt_lo[idx] = f2bf(w - bf2f(h));
    } else {
        int j = idx - 384 * 128;
        int n = j >> 7, k = j & 127;
        float w = wp[k * 128 + n];
        unsigned short h = f2bf(w);
        Wpt_hi[j] = h;
        Wpt_lo[j] = f2bf(w - bf2f(h));
    }
}

// ---------------- Kernel 1: QK + V projection via split-bf16 MFMA ----------------
#define ASTR 136   // 128 k + 8 pad (keeps 16B units, spreads bank quads)
__global__ __launch_bounds__(256) void k_projm(
    const float* __restrict__ x, const unsigned short* __restrict__ Wt_hi,
    const unsigned short* __restrict__ Wt_lo, const float* __restrict__ b_qk,
    const float* __restrict__ b_v, float* __restrict__ qk, float* __restrict__ vout)
{
    __shared__ unsigned short A[2][64 * ASTR + 8];   // [hi/lo][px][k]
    const int tid = threadIdx.x, lane = tid & 63, w = tid >> 6;
    const int blk = blockIdx.x;
    const int b = blk >> 8;
    const int p0 = (blk & 255) << 6;                 // 64 consecutive pixels
    const float* xb = x + (size_t)b * CC * HWW + p0;
    // stage x tile -> bf16 hi/lo, transposed to [px][k]; lanes c-major (conflict-free writes)
    {
        const int cp = (w << 4) + (lane & 15);       // channel pair 0..63
        const int c0 = cp << 1;
        const float* s0p = xb + (size_t)c0 * HWW;
        const float* s1p = s0p + HWW;
        #pragma unroll
        for (int it = 0; it < 16; ++it) {
            int px = (lane >> 4) + (it << 2);
            float f0 = s0p[px], f1 = s1p[px];
            unsigned short h0 = f2bf(f0), h1 = f2bf(f1);
            unsigned short l0 = f2bf(f0 - bf2f(h0)), l1 = f2bf(f1 - bf2f(h1));
            *(unsigned int*)&A[0][px * ASTR + c0] = (unsigned)h0 | ((unsigned)h1 << 16);
            *(unsigned int*)&A[1][px * ASTR + c0] = (unsigned)l0 | ((unsigned)l1 << 16);
        }
    }
    __syncthreads();
    const int g = lane >> 4, r = lane & 15;
    const int nbase = 96 * w;                        // wave owns 96 n-cols
    f32x4 acc[4][6];
    #pragma unroll
    for (int nt = 0; nt < 6; ++nt) {
        int n = nbase + nt * 16 + r;
        float bv = (n < 256) ? b_qk[n] : b_v[n - 256];
        #pragma unroll
        for (int mt = 0; mt < 4; ++mt) acc[mt][nt] = (f32x4){bv, bv, bv, bv};
    }
    // virtual K = 384: phase0 x_hi*W_hi, phase1 x_lo*W_hi, phase2 x_hi*W_lo
    for (int phase = 0; phase < 3; ++phase) {
        const unsigned short* Wt = (phase == 2) ? Wt_lo : Wt_hi;
        const unsigned short* Ab = (phase == 1) ? A[1] : A[0];
        #pragma unroll
        for (int kc = 0; kc < 4; ++kc) {
            const int kk = kc * 32 + g * 8;
            bf16x8 bfr[6];
            #pragma unroll
            for (int nt = 0; nt < 6; ++nt) {
                int n = nbase + nt * 16 + r;
                bfr[nt] = *(const bf16x8*)(Wt + (size_t)n * 128 + kk);
            }
            bf16x8 afr[4];
            #pragma unroll
            for (int mt = 0; mt < 4; ++mt)
                afr[mt] = *(const bf16x8*)(&Ab[(mt * 16 + r) * ASTR + kk]);
            #pragma unroll
            for (int mt = 0; mt < 4; ++mt) {
                #pragma unroll
                for (int nt = 0; nt < 6; ++nt)
                    acc[mt][nt] = MFMA16(afr[mt], bfr[nt], acc[mt][nt]);
            }
        }
    }
    const size_t pb = (size_t)b * HWW + p0;
    #pragma unroll
    for (int nt = 0; nt < 6; ++nt) {
        int n = nbase + nt * 16 + r;
        float* base; int str;
        if (n < 256) { base = qk + pb * 256 + n; str = 256; }
        else         { base = vout + pb * 128 + (n - 256); str = 128; }
        #pragma unroll
        for (int mt = 0; mt < 4; ++mt) {
            int prow = mt * 16 + g * 4;
            #pragma unroll
            for (int j = 0; j < 4; ++j)
                base[(size_t)(prow + j) * str] = acc[mt][nt][j];
        }
    }
}

// ---------------- Kernel 2: superpixel-similarity dots (pwd) ----------------
#define SSTR 260
__global__ __launch_bounds__(256) void k_pwd(
    const float* __restrict__ sims, float* __restrict__ pwd)
{
    extern __shared__ float Ss[];            // [144][SSTR]
    const int tid = threadIdx.x;
    const int blk = blockIdx.x;
    const int b = blk >> 8, tile = blk & 255;
    const int i0 = (tile >> 4) << 3, j0 = (tile & 15) << 3;
    #pragma unroll 6
    for (int it = 0; it < 36; ++it) {
        int idx = tid + it * 256;
        int vec = idx >> 6, s4 = (idx & 63) << 2;
        int hi = vec / 12, wj = vec - hi * 12;
        int ii = i0 - 2 + hi, jj = j0 - 2 + wj;
        float4 val = make_float4(0.f, 0.f, 0.f, 0.f);
        if ((unsigned)ii < 128u && (unsigned)jj < 128u)
            val = *(const float4*)(sims + ((((size_t)b * HH + ii) * WW + jj) << 8) + s4);
        *(float4*)(Ss + vec * SSTR + s4) = val;
    }
    __syncthreads();
    const int px = tid & 63, og = tid >> 6;
    const int pi = px >> 3, pj = px & 7;
    const float* selfp = Ss + ((pi + 2) * 12 + (pj + 2)) * SSTR;
    const int noffs = (og == 0) ? 7 : 6;
    const float* nb[7];
    int offl[7];
    #pragma unroll
    for (int m = 0; m < 7; ++m) {
        int off = og + (m << 2);
        if (off > 24) off = 24;
        offl[m] = off;
        int di = off / 5, dj = off - 5 * di;
        nb[m] = Ss + ((pi + di) * 12 + (pj + dj)) * SSTR;
    }
    float acc[7] = {0.f,0.f,0.f,0.f,0.f,0.f,0.f};
    for (int s0 = 0; s0 < 256; s0 += 16) {
        float4 a0 = *(const float4*)(selfp + s0);
        float4 a1 = *(const float4*)(selfp + s0 + 4);
        float4 a2 = *(const float4*)(selfp + s0 + 8);
        float4 a3 = *(const float4*)(selfp + s0 + 12);
        #pragma unroll
        for (int m = 0; m < 7; ++m) {
            if (m < noffs) {
                const float4* q = (const float4*)(nb[m] + s0);
                float4 b0 = q[0], b1 = q[1], b2 = q[2], b3 = q[3];
                float s = acc[m];
                s = fmaf(a0.x, b0.x, s); s = fmaf(a0.y, b0.y, s);
                s = fmaf(a0.z, b0.z, s); s = fmaf(a0.w, b0.w, s);
                s = fmaf(a1.x, b1.x, s); s = fmaf(a1.y, b1.y, s);
                s = fmaf(a1.z, b1.z, s); s = fmaf(a1.w, b1.w, s);
                s = fmaf(a2.x, b2.x, s); s = fmaf(a2.y, b2.y, s);
                s = fmaf(a2.z, b2.z, s); s = fmaf(a2.w, b2.w, s);
                s = fmaf(a3.x, b3.x, s); s = fmaf(a3.y, b3.y, s);
                s = fmaf(a3.z, b3.z, s); s = fmaf(a3.w, b3.w, s);
                acc[m] = s;
            }
        }
    }
    const int p = b * HWW + (i0 + pi) * WW + (j0 + pj);
    #pragma unroll
    for (int m = 0; m < 7; ++m)
        if (m < noffs) pwd[offl[m] * PTOT + p] = acc[m];
}

// ---------------- Kernel 3: scores + softmax + pwd reweight + V aggregation ----------------
#define KSTR 132
__device__ __forceinline__ void stage_halo(
    float* Hs, const float* __restrict__ src, int pxstride, int b, int i0, int j0, int tid)
{
    #pragma unroll 6
    for (int it = 0; it < 18; ++it) {
        int idx = tid + it * 256;
        int vec = idx >> 5, c4 = (idx & 31) << 2;
        int hi = vec / 12, wj = vec - hi * 12;
        int ii = i0 - 2 + hi, jj = j0 - 2 + wj;
        float4 val = make_float4(0.f, 0.f, 0.f, 0.f);
        if ((unsigned)ii < 128u && (unsigned)jj < 128u)
            val = *(const float4*)(src + (((size_t)b * HH + ii) * WW + jj) * (size_t)pxstride + c4);
        *(float4*)(Hs + vec * KSTR + c4) = val;
    }
}

__global__ __launch_bounds__(256) void k_attn(
    const float* __restrict__ qk, const float* __restrict__ vbuf,
    const float* __restrict__ pwd, float* __restrict__ y)
{
    extern __shared__ float Hs[];
    const int tid = threadIdx.x, blk = blockIdx.x;
    const int b = blk >> 8, tile = blk & 255;
    const int i0 = (tile >> 4) << 3, j0 = (tile & 15) << 3;
    stage_halo(Hs, qk + 128, 256, b, i0, j0, tid);      // K halo
    __syncthreads();
    const int px = tid & 63, h = tid >> 6;
    const int pi = px >> 3, pj = px & 7;
    const int p = b * HWW + (i0 + pi) * WW + (j0 + pj);
    const float* qb = qk + (size_t)p * 256 + h * 32;
    const float* hb = Hs + (pi * 12 + pj) * KSTR + h * 32;
    float sc[25];
    #pragma unroll
    for (int o = 0; o < 25; ++o) sc[o] = 0.f;
    #pragma unroll
    for (int ec = 0; ec < 4; ++ec) {
        float4 q0 = *(const float4*)(qb + ec * 8);
        float4 q1 = *(const float4*)(qb + ec * 8 + 4);
        #pragma unroll
        for (int off = 0; off < 25; ++off) {
            const int voff = (off / 5) * 12 + (off % 5);
            const float* kp = hb + voff * KSTR + ec * 8;
            float4 k0 = *(const float4*)(kp);
            float4 k1 = *(const float4*)(kp + 4);
            float s = sc[off];
            s = fmaf(q0.x, k0.x, s); s = fmaf(q0.y, k0.y, s);
            s = fmaf(q0.z, k0.z, s); s = fmaf(q0.w, k0.w, s);
            s = fmaf(q1.x, k1.x, s); s = fmaf(q1.y, k1.y, s);
            s = fmaf(q1.z, k1.z, s); s = fmaf(q1.w, k1.w, s);
            sc[off] = s;
        }
    }
    float mx = sc[0];
    #pragma unroll
    for (int o = 1; o < 25; ++o) mx = fmaxf(mx, sc[o]);
    float den = 0.f;
    #pragma unroll
    for (int o = 0; o < 25; ++o) {
        sc[o] = __expf((sc[o] - mx) * 0.17677669529663687f);
        den += sc[o];
    }
    const float inv = 1.f / den;
    float den2 = 0.f;
    #pragma unroll
    for (int o = 0; o < 25; ++o) {
        float t = sc[o] * inv * pwd[o * PTOT + p];
        sc[o] = t; den2 += t;
    }
    const float wnorm = 1.f / fmaxf(den2, 1e-8f);
    #pragma unroll
    for (int o = 0; o < 25; ++o) sc[o] *= wnorm;
    __syncthreads();
    stage_halo(Hs, vbuf, 128, b, i0, j0, tid);          // V halo
    __syncthreads();
    float4* yo = (float4*)(y + (size_t)p * 128 + h * 32);
    #pragma unroll
    for (int ec = 0; ec < 4; ++ec) {
        float4 a0 = make_float4(0.f, 0.f, 0.f, 0.f);
        float4 a1 = make_float4(0.f, 0.f, 0.f, 0.f);
        #pragma unroll
        for (int off = 0; off < 25; ++off) {
            const int voff = (off / 5) * 12 + (off % 5);
            const float* vp = hb + voff * KSTR + ec * 8;
            float4 v0 = *(const float4*)(vp);
            float4 v1 = *(const float4*)(vp + 4);
            float w = sc[off];
            a0.x = fmaf(w, v0.x, a0.x); a0.y = fmaf(w, v0.y, a0.y);
            a0.z = fmaf(w, v0.z, a0.z); a0.w = fmaf(w, v0.w, a0.w);
            a1.x = fmaf(w, v1.x, a1.x); a1.y = fmaf(w, v1.y, a1.y);
            a1.z = fmaf(w, v1.z, a1.z); a1.w = fmaf(w, v1.w, a1.w);
        }
        yo[ec * 2] = a0;
        yo[ec * 2 + 1] = a1;
    }
}

// ---------------- Kernel 4: output projection via split-bf16 MFMA + NCHW ----------------
__global__ __launch_bounds__(256) void k_outm(
    const float* __restrict__ y, const unsigned short* __restrict__ Wpt_hi,
    const unsigned short* __restrict__ Wpt_lo, const float* __restrict__ b_proj,
    float* __restrict__ out)
{
    __shared__ unsigned short A[2][64 * ASTR + 8];
    const int tid = threadIdx.x, lane = tid & 63, w = tid >> 6;
    const int blk = blockIdx.x;
    const int b = blk >> 8;
    const int p0 = (blk & 255) << 6;
    const float* yb = y + ((size_t)b * HWW + p0) * 128;
    // stage y tile (already [px][c] c-contiguous): float4 loads, b64 bf16 writes
    #pragma unroll
    for (int it = 0; it < 8; ++it) {
        int idx = tid + it * 256;
        int px = idx >> 5, c4 = (idx & 31) << 2;
        float4 f = *(const float4*)(yb + (size_t)px * 128 + c4);
        unsigned short h0 = f2bf(f.x), h1 = f2bf(f.y), h2 = f2bf(f.z), h3 = f2bf(f.w);
        u16x4 hv = {h0, h1, h2, h3};
        u16x4 lv = {f2bf(f.x - bf2f(h0)), f2bf(f.y - bf2f(h1)),
                    f2bf(f.z - bf2f(h2)), f2bf(f.w - bf2f(h3))};
        *(u16x4*)&A[0][px * ASTR + c4] = hv;
        *(u16x4*)&A[1][px * ASTR + c4] = lv;
    }
    __syncthreads();
    const int g = lane >> 4, r = lane & 63 & 15;
    const int nbase = 32 * w;                 // wave owns 32 n-cols
    f32x4 acc[4][2];
    #pragma unroll
    for (int nt = 0; nt < 2; ++nt) {
        float bv = b_proj[nbase + nt * 16 + r];
        #pragma unroll
        for (int mt = 0; mt < 4; ++mt) acc[mt][nt] = (f32x4){bv, bv, bv, bv};
    }
    for (int phase = 0; phase < 3; ++phase) {
        const unsigned short* Wt = (phase == 2) ? Wpt_lo : Wpt_hi;
        const unsigned short* Ab = (phase == 1) ? A[1] : A[0];
        #pragma unroll
        for (int kc = 0; kc < 4; ++kc) {
            const int kk = kc * 32 + g * 8;
            bf16x8 bfr[2];
            #pragma unroll
            for (int nt = 0; nt < 2; ++nt) {
                int n = nbase + nt * 16 + r;
                bfr[nt] = *(const bf16x8*)(Wt + (size_t)n * 128 + kk);
            }
            bf16x8 afr[4];
            #pragma unroll
            for (int mt = 0; mt < 4; ++mt)
                afr[mt] = *(const bf16x8*)(&Ab[(mt * 16 + r) * ASTR + kk]);
            #pragma unroll
            for (int mt = 0; mt < 4; ++mt) {
                #pragma unroll
                for (int nt = 0; nt < 2; ++nt)
                    acc[mt][nt] = MFMA16(afr[mt], bfr[nt], acc[mt][nt]);
            }
        }
    }
    __syncthreads();                          // done reading A; reuse as transpose buffer
    float* Ts = (float*)A;                    // [n=128][px stride 68]
    #pragma unroll
    for (int nt = 0; nt < 2; ++nt) {
        int n = nbase + nt * 16 + r;
        #pragma unroll
        for (int mt = 0; mt < 4; ++mt) {
            int prow = mt * 16 + g * 4;
            #pragma unroll
            for (int j = 0; j < 4; ++j)
                Ts[n * 68 + prow + j] = acc[mt][nt][j];
        }
    }
    __syncthreads();
    #pragma unroll
    for (int it = 0; it < 32; ++it) {
        int idx = tid + it * 256;
        int n = idx >> 6, px = idx & 63;
        out[((size_t)b * CC + n) * HWW + p0 + px] = Ts[n * 68 + px];
    }
}

extern "C" void kernel_launch(void* const* d_in, const int* in_sizes, int n_in,
                              void* d_out, int out_size, void* d_ws, size_t ws_size,
                              hipStream_t stream) {
    (void)in_sizes; (void)n_in; (void)out_size; (void)ws_size;
    const float* x      = (const float*)d_in[0];
    const float* sims   = (const float*)d_in[1];
    const float* w_qk   = (const float*)d_in[2];
    const float* b_qk   = (const float*)d_in[3];
    const float* w_v    = (const float*)d_in[4];
    const float* b_v    = (const float*)d_in[5];
    const float* w_proj = (const float*)d_in[6];
    const float* b_proj = (const float*)d_in[7];
    float* out = (float*)d_out;
    float* ws  = (float*)d_ws;
    float* qk  = ws;                         // 33,554,432 f
    float* v   = ws + 33554432ull;           // 16,777,216 f
    float* pwd = ws + 50331648ull;           //  3,276,800 f  [off][p]
    float* y   = ws + 53608448ull;           // 16,777,216 f -> end 70,385,664 f
    // Wt_hi/lo live in the TAIL of y: prep+k_projm use them BEFORE k_attn writes y
    unsigned short* Wt_hi  = (unsigned short*)(ws + 70336512ull);  // 49,152 bf16
    unsigned short* Wt_lo  = (unsigned short*)(ws + 70361088ull);  // 49,152 bf16
    // Wpt must survive until k_outm: appended after y (+64 KB)
    unsigned short* Wpt_hi = (unsigned short*)(ws + 70385664ull);  // 16,384 bf16
    unsigned short* Wpt_lo = (unsigned short*)(ws + 70393856ull);  // 16,384 bf16
    dim3 blkd(256);
    hipLaunchKernelGGL(k_prep,  dim3(256),  blkd, 0, stream, w_qk, w_v, w_proj,
                       Wt_hi, Wt_lo, Wpt_hi, Wpt_lo);
    hipLaunchKernelGGL(k_projm, dim3(2048), blkd, 0, stream, x, Wt_hi, Wt_lo,
                       b_qk, b_v, qk, v);
    hipLaunchKernelGGL(k_pwd,   dim3(2048), blkd, 144 * SSTR * 4, stream, sims, pwd);
    hipLaunchKernelGGL(k_attn,  dim3(2048), blkd, 144 * KSTR * 4, stream, qk, v, pwd, y);
    hipLaunchKernelGGL(k_outm,  dim3(2048), blkd, 0, stream, y, Wpt_hi, Wpt_lo,
                       b_proj, out);
}